// Round 12
// baseline (318.108 us; speedup 1.0000x reference)
//
#include <hip/hip_runtime.h>

#define GRID_RES 256
#define NCELLS 1024            // 8 x 8 x 16 cells of 32 x 32 x 16 voxels
#define NB 1024                // binning blocks
#define BCAP 6144              // per-block LDS staging capacity (items; expected ~5100 padded)
#define CCAP 6144              // per-cell global region capacity (even; expected ~5900 max)
#define NPT 2                  // points per thread in bin (chunk 1954 <= 2*1024)

#define W_SCALE 2097152.0f     // 2^21 fixed-point for voxel weights
#define INV_W (1.0f / 2097152.0f)
#define L_SCALE 512.0f         // 2^9 fixed-point for the loss accumulator
#define INV_L (1.0f / 512.0f)

// 4-byte packed event item:
//   bits [0,5)   qx (fx * 31, RN)        dequant * (1/31)
//   bits [5,10)  qy (fy * 31, RN)
//   bits [10,14) qz (fz * 15, RN)        dequant * (1/15)
//   bits [14,20) lx in [0,32]  (base-cell local coords, biased +1)
//   bits [20,26) ly in [0,32]
//   bits [26,31) lz in [0,16]
//   bit  31      sign (0 = pred +, 1 = gt -)
struct CEv { unsigned pk, xyz; };

__device__ __forceinline__ CEv make_cev(float px, float py, float pz,
                                        unsigned sign) {
    float x = ((px + 1.0f) * (float)GRID_RES - 1.0f) * 0.5f;
    float y = ((py + 1.0f) * (float)GRID_RES - 1.0f) * 0.5f;
    float z = ((pz + 1.0f) * (float)GRID_RES - 1.0f) * 0.5f;
    float xf = floorf(x), yf = floorf(y), zf = floorf(z);
    int x0 = (int)xf, y0 = (int)yf, z0 = (int)zf;
    unsigned qx = (unsigned)((x - xf) * 31.0f + 0.5f);   // 0..31
    unsigned qy = (unsigned)((y - yf) * 31.0f + 0.5f);   // 0..31
    unsigned qz = (unsigned)((z - zf) * 15.0f + 0.5f);   // 0..15
    bool valid = (x0 >= -1) & (x0 <= 255) & (y0 >= -1) & (y0 <= 255) &
                 (z0 >= -1) & (z0 <= 255);
    CEv e;
    e.pk = qx | (qy << 5) | (qz << 10) | (sign << 31);
    e.xyz = valid ? ((unsigned)(x0 + 1) | ((unsigned)(y0 + 1) << 10) |
                     ((unsigned)(z0 + 1) << 20) | (1u << 30))
                  : 0u;
    return e;
}

// Flat decode for branch-free 8-corner cell enumeration.
// cell0 = base cell; bx/by/bz = "second cell exists" per axis;
// w1base = pk with base-cell local coords OR'd in (lx0 = 32 whenever bx,
// so the per-corner field subtraction never borrows).
__device__ __forceinline__ bool ev_flat(const CEv& e, unsigned& cell0,
                                        unsigned& w1base, bool& bx, bool& by,
                                        bool& bz) {
    if (!(e.xyz & (1u << 30))) return false;
    int x0 = (int)(e.xyz & 1023u) - 1;
    int y0 = (int)((e.xyz >> 10) & 1023u) - 1;
    int z0 = (int)((e.xyz >> 20) & 1023u) - 1;
    int xlo = (x0 >= 0) ? (x0 >> 5) : 0;
    int ylo = (y0 >= 0) ? (y0 >> 5) : 0;
    int zlo = (z0 >= 0) ? (z0 >> 4) : 0;
    bx = ((x0 & 31) == 31) & ((unsigned)x0 < 255u);
    by = ((y0 & 31) == 31) & ((unsigned)y0 < 255u);
    bz = ((z0 & 15) == 15) & ((unsigned)z0 < 255u);
    cell0 = ((unsigned)zlo << 6) | ((unsigned)ylo << 3) | (unsigned)xlo;
    unsigned lx0 = (unsigned)(x0 - (xlo << 5) + 1);
    unsigned ly0 = (unsigned)(y0 - (ylo << 5) + 1);
    unsigned lz0 = (unsigned)(z0 - (zlo << 4) + 1);
    w1base = e.pk | (lx0 << 14) | (ly0 << 20) | (lz0 << 26);
    return true;
}

__global__ void init_kernel(unsigned* __restrict__ gCursor,
                            int* __restrict__ lossAcc,
                            unsigned* __restrict__ doneCnt) {
    int t = threadIdx.x;
    gCursor[t] = 0;
    if (t == 0) { lossAcc[0] = 0; doneCnt[0] = 0; }
}

// Binning: LDS histogram -> even-padded scan -> global per-cell reservation
// (latency hidden under the LDS scatter) -> LDS scatter (4 B items + u16
// cell tag; zero-sentinel pad per odd run) -> uint2 writeout (2 items, 8 B,
// pairs never straddle runs) to CELL-CONTIGUOUS global layout.
// NOTE (round-11 A/B): direct scattered 4 B global stores instead of this
// staging cost +21 us and +35 MB WRITE_SIZE -- staging is load-bearing.
__global__ __launch_bounds__(1024) void bin_kernel(
    const float* __restrict__ pred, const float* __restrict__ gt,
    const float* __restrict__ coords, unsigned* __restrict__ gCursor,
    unsigned* __restrict__ payload, int n) {
    __shared__ unsigned h[NCELLS];            // 4 KB (histogram, then cursor)
    __shared__ unsigned gAdj[NCELLS];         // 4 KB dest-adjust per cell
    __shared__ unsigned short itemCell[BCAP]; // 12 KB cell tag per staged item
    __shared__ unsigned wtot[16];
    __shared__ unsigned totalS;
    __shared__ unsigned pl[BCAP];             // 24 KB payload staging (4 B/item)
    int b = blockIdx.x;
    int t = threadIdx.x;
    h[t] = 0;
    __syncthreads();

    int chunk = (n + NB - 1) / NB;
    int start = b * chunk;
    int end = min(start + chunk, n);
    const float3* c3 = (const float3*)coords;
    const float3* p3 = (const float3*)pred;
    const float3* g3 = (const float3*)gt;

    CEv ev[2 * NPT];
#pragma unroll
    for (int k = 0; k < NPT; ++k) {
        int i = start + t + (k << 10);
        if (i < end) {
            float3 c = c3[i];
            float3 p = p3[i];
            float3 g = g3[i];
            ev[2 * k] = make_cev(c.x + p.x, c.y + p.y, c.z + p.z, 0u);
            ev[2 * k + 1] = make_cev(c.x + g.x, c.y + g.y, c.z + g.z, 1u);
        } else {
            ev[2 * k].xyz = 0;
            ev[2 * k + 1].xyz = 0;
        }
    }

    // pass 1: histogram (branch-free 8-corner, predicated LDS atomics)
#pragma unroll
    for (int k = 0; k < 2 * NPT; ++k) {
        unsigned cell0, w1base;
        bool bx, by, bz;
        if (ev_flat(ev[k], cell0, w1base, bx, by, bz)) {
#pragma unroll
            for (int q = 0; q < 8; ++q) {
                const int DX = q & 1, DY = (q >> 1) & 1, DZ = q >> 2;
                bool go = (DX ? bx : true) & (DY ? by : true) & (DZ ? bz : true);
                if (go) atomicAdd(&h[cell0 + DX + 8 * DY + 64 * DZ], 1u);
            }
        }
    }
    __syncthreads();

    // exclusive scan over EVEN-PADDED counts (xp = x rounded up to even)
    unsigned x = h[t];
    unsigned xp = x + (x & 1u);
    unsigned incl = xp;
    int lane = t & 63, wid = t >> 6;
#pragma unroll
    for (int off = 1; off < 64; off <<= 1) {
        unsigned y = __shfl_up(incl, off, 64);
        if (lane >= off) incl += y;
    }
    if (lane == 63) wtot[wid] = incl;
    __syncthreads();
    if (t == 0) {
        unsigned r = 0;
#pragma unroll
        for (int w = 0; w < 16; ++w) { unsigned q = wtot[w]; wtot[w] = r; r += q; }
        totalS = r;
    }
    __syncthreads();
    unsigned offE = incl - xp + wtot[wid];  // even
    h[t] = offE;  // reuse as scatter cursor

    // zero-sentinel pad for odd runs (pk=0 decodes to exact-zero weights:
    // all fractions 0 -> every surviving corner gets iw = round(0) = 0)
    if ((x & 1u) && (offE + x) < (unsigned)BCAP) {
        pl[offE + x] = 0u;
        itemCell[offE + x] = (unsigned short)t;
    }

    // global per-cell reservation of the PADDED count (latency hidden under
    // the scatter phase)
    unsigned gdst = atomicAdd(&gCursor[t], xp);  // even since all xp even
    gAdj[t] = (unsigned)t * (unsigned)CCAP + gdst - offE;  // even; u32 wrap ok
    __syncthreads();

    // pass 2: scatter into LDS staging + cell tag (branch-free 8-corner;
    // per-corner w1 is a constant field subtraction off w1base)
#pragma unroll
    for (int k = 0; k < 2 * NPT; ++k) {
        unsigned cell0, w1base;
        bool bx, by, bz;
        if (ev_flat(ev[k], cell0, w1base, bx, by, bz)) {
#pragma unroll
            for (int q = 0; q < 8; ++q) {
                const int DX = q & 1, DY = (q >> 1) & 1, DZ = q >> 2;
                bool go = (DX ? bx : true) & (DY ? by : true) & (DZ ? bz : true);
                if (go) {
                    unsigned cell = cell0 + DX + 8 * DY + 64 * DZ;
                    unsigned w1 = w1base - (((unsigned)DX << 19) +
                                            ((unsigned)DY << 25) +
                                            ((unsigned)DZ << 30));
                    unsigned slot = atomicAdd(&h[cell], 1u);
                    if (slot < (unsigned)BCAP) {
                        pl[slot] = w1;
                        itemCell[slot] = (unsigned short)cell;
                    }
                }
            }
        }
    }
    __syncthreads();

    // writeout: uint2 stores (2 items, 8 B; pairs never straddle runs)
    unsigned tot = min(totalS, (unsigned)BCAP);
    unsigned np = tot >> 1;
    const uint2* pl2 = (const uint2*)pl;
    uint2* pay2 = (uint2*)payload;
    for (unsigned j = t; j < np; j += 1024) {
        unsigned cell = itemCell[2 * j];
        unsigned e = gAdj[cell] + 2u * j;   // even element index
        if (e + 2u <= (cell + 1u) * (unsigned)CCAP) pay2[e >> 1] = pl2[j];
    }
}

__device__ __forceinline__ void accum_item(unsigned p, int* v) {
    float fx = (float)(p & 31u) * (1.0f / 31.0f);
    float fy = (float)((p >> 5) & 31u) * (1.0f / 31.0f);
    float fz = (float)((p >> 10) & 15u) * (1.0f / 15.0f);
    int lx = (int)((p >> 14) & 63u);
    int ly = (int)((p >> 20) & 63u);
    int lz = (int)((p >> 26) & 31u);
    float s = (p >> 31) ? -W_SCALE : W_SCALE;
    float wxs[2] = {1.0f - fx, fx};
    float wys[2] = {1.0f - fy, fy};
    float wzs[2] = {1.0f - fz, fz};
    int xb = lx - 1, yb = ly - 1, zb = lz - 1;
#pragma unroll
    for (int dz = 0; dz < 2; ++dz) {
        int rz = zb + dz;
        if ((unsigned)rz > 15u) continue;
        float wz = s * wzs[dz];
#pragma unroll
        for (int dy = 0; dy < 2; ++dy) {
            int ry = yb + dy;
            if ((unsigned)ry > 31u) continue;
            float wyz = wz * wys[dy];
#pragma unroll
            for (int dx = 0; dx < 2; ++dx) {
                int rx = xb + dx;
                if ((unsigned)rx > 31u) continue;
                int iw = __float2int_rn(wyz * wxs[dx]);
                atomicAdd(&v[(rz << 10) | (ry << 5) | rx], iw);  // ds_add, no ret
            }
        }
    }
}

// One block per cell: payload is cell-contiguous -> pure streaming uint2
// reads (2 items each, unroll 4 for 8 decodes in flight), zero indirection.
// Count is even (padded); sentinels add exactly zero. Loss epilogue: direct
// per-wave global atomics (no wsum staging / extra barrier).
__global__ __launch_bounds__(1024) void accum_kernel(
    const unsigned* __restrict__ payload, const unsigned* __restrict__ gCursor,
    int* __restrict__ lossAcc, unsigned* __restrict__ doneCnt,
    float* __restrict__ out) {
    __shared__ int4 v4s[4096];                   // 64 KB accumulation grid
    int* v = (int*)v4s;
    int c = blockIdx.x;
    int t = threadIdx.x;
    unsigned cnt = min(gCursor[c], (unsigned)CCAP) & ~1u;  // uniform: s_load
    int4 z; z.x = 0; z.y = 0; z.z = 0; z.w = 0;
#pragma unroll
    for (int j = 0; j < 4; ++j) v4s[t + (j << 10)] = z;
    __syncthreads();

    const uint2* p2 = (const uint2*)(payload + (size_t)c * CCAP);  // 8B aligned
    unsigned n2 = cnt >> 1;
#pragma unroll 4
    for (unsigned i = t; i < n2; i += 1024) {
        uint2 q = p2[i];
        accum_item(q.x, v);
        accum_item(q.y, v);
    }
    __syncthreads();

    int lane = t & 63;
    float acc = 0.0f;
#pragma unroll
    for (int j = 0; j < 4; ++j) {
        int4 q = v4s[t + (j << 10)];
        {
            float d = (float)q.x * INV_W;
            float ad = fabsf(d);
            acc += (ad <= 1.0f) ? 0.5f * d * d : ad - 0.5f;
        }
        {
            float d = (float)q.y * INV_W;
            float ad = fabsf(d);
            acc += (ad <= 1.0f) ? 0.5f * d * d : ad - 0.5f;
        }
        {
            float d = (float)q.z * INV_W;
            float ad = fabsf(d);
            acc += (ad <= 1.0f) ? 0.5f * d * d : ad - 0.5f;
        }
        {
            float d = (float)q.w * INV_W;
            float ad = fabsf(d);
            acc += (ad <= 1.0f) ? 0.5f * d * d : ad - 0.5f;
        }
    }
#pragma unroll
    for (int o = 32; o > 0; o >>= 1) acc += __shfl_down(acc, o, 64);
    if (lane == 0) atomicAdd(lossAcc, __float2int_rn(acc * L_SCALE));
    __syncthreads();  // all waves' loss atomics issued before done-signal
    if (t == 0) {
        __threadfence();
        unsigned done = atomicAdd(doneCnt, 1u);
        if (done == (unsigned)(NCELLS - 1)) {   // last block finalizes
            __threadfence();
            int lv = atomicAdd(lossAcc, 0);
            out[0] = (float)lv * INV_L;
        }
    }
}

extern "C" void kernel_launch(void* const* d_in, const int* in_sizes, int n_in,
                              void* d_out, int out_size, void* d_ws, size_t ws_size,
                              hipStream_t stream) {
    const float* reg_pred = (const float*)d_in[0];
    const float* reg_gt   = (const float*)d_in[1];
    const float* coords   = (const float*)d_in[2];
    float* out = (float*)d_out;

    char* ws = (char*)d_ws;
    int* lossAcc = (int*)ws;                                  // 4 B
    unsigned* doneCnt = (unsigned*)(ws + 64);                 // 4 B
    unsigned* gCursor = (unsigned*)(ws + 256);                // 4 KiB
    unsigned* payload = (unsigned*)(ws + 256 + 4096);         // 24 MiB

    int n = in_sizes[0] / 3;  // 2,000,000 points

    init_kernel<<<1, 1024, 0, stream>>>(gCursor, lossAcc, doneCnt);
    bin_kernel<<<NB, 1024, 0, stream>>>(reg_pred, reg_gt, coords, gCursor,
                                        payload, n);
    accum_kernel<<<NCELLS, 1024, 0, stream>>>(payload, gCursor, lossAcc,
                                              doneCnt, out);
}

// Round 13
// 156.460 us; speedup vs baseline: 2.0332x; 2.0332x over previous
//
#include <hip/hip_runtime.h>

#define GRID_RES 256
#define NCELLS 1024            // 8 x 8 x 16 cells of 32 x 32 x 16 voxels
#define NB 1024                // binning blocks
#define BCAP 6144              // per-block LDS staging capacity (items; expected ~5100 padded)
#define CCAP 6144              // per-cell global region capacity (even; expected ~5900 max)
#define NPT 2                  // points per thread in bin (chunk 1954 <= 2*1024)

#define W_SCALE 2097152.0f     // 2^21 fixed-point for voxel weights
#define INV_W (1.0f / 2097152.0f)
#define L_SCALE 512.0f         // 2^9 fixed-point for the loss accumulator
#define INV_L (1.0f / 512.0f)

// 4-byte packed event item:
//   bits [0,5)   qx (fx * 31, RN)        dequant * (1/31)
//   bits [5,10)  qy (fy * 31, RN)
//   bits [10,14) qz (fz * 15, RN)        dequant * (1/15)
//   bits [14,20) lx in [0,32]  (base-cell local coords, biased +1)
//   bits [20,26) ly in [0,32]
//   bits [26,31) lz in [0,16]
//   bit  31      sign (0 = pred +, 1 = gt -)
// NOTE (round-12 A/B): per-wave global atomics on lossAcc (16K same-address
// device-scope atomics) serialized cross-XCD and cost +150 us -- keep the
// per-block wsum reduction + ONE atomic per block (Guideline 12).
// NOTE (round-11 A/B): direct scattered 4 B global stores instead of LDS
// staging cost +21 us and +35 MB WRITE_SIZE -- staging is load-bearing.
struct CEv { unsigned pk, xyz; };

__device__ __forceinline__ CEv make_cev(float px, float py, float pz,
                                        unsigned sign) {
    float x = ((px + 1.0f) * (float)GRID_RES - 1.0f) * 0.5f;
    float y = ((py + 1.0f) * (float)GRID_RES - 1.0f) * 0.5f;
    float z = ((pz + 1.0f) * (float)GRID_RES - 1.0f) * 0.5f;
    float xf = floorf(x), yf = floorf(y), zf = floorf(z);
    int x0 = (int)xf, y0 = (int)yf, z0 = (int)zf;
    unsigned qx = (unsigned)((x - xf) * 31.0f + 0.5f);   // 0..31
    unsigned qy = (unsigned)((y - yf) * 31.0f + 0.5f);   // 0..31
    unsigned qz = (unsigned)((z - zf) * 15.0f + 0.5f);   // 0..15
    bool valid = (x0 >= -1) & (x0 <= 255) & (y0 >= -1) & (y0 <= 255) &
                 (z0 >= -1) & (z0 <= 255);
    CEv e;
    e.pk = qx | (qy << 5) | (qz << 10) | (sign << 31);
    e.xyz = valid ? ((unsigned)(x0 + 1) | ((unsigned)(y0 + 1) << 10) |
                     ((unsigned)(z0 + 1) << 20) | (1u << 30))
                  : 0u;
    return e;
}

// Flat decode for branch-free 8-corner cell enumeration.
// cell0 = base cell; bx/by/bz = "second cell exists" per axis;
// w1base = pk with base-cell local coords OR'd in (lx0 = 32 whenever bx,
// so the per-corner field subtraction never borrows).
__device__ __forceinline__ bool ev_flat(const CEv& e, unsigned& cell0,
                                        unsigned& w1base, bool& bx, bool& by,
                                        bool& bz) {
    if (!(e.xyz & (1u << 30))) return false;
    int x0 = (int)(e.xyz & 1023u) - 1;
    int y0 = (int)((e.xyz >> 10) & 1023u) - 1;
    int z0 = (int)((e.xyz >> 20) & 1023u) - 1;
    int xlo = (x0 >= 0) ? (x0 >> 5) : 0;
    int ylo = (y0 >= 0) ? (y0 >> 5) : 0;
    int zlo = (z0 >= 0) ? (z0 >> 4) : 0;
    bx = ((x0 & 31) == 31) & ((unsigned)x0 < 255u);
    by = ((y0 & 31) == 31) & ((unsigned)y0 < 255u);
    bz = ((z0 & 15) == 15) & ((unsigned)z0 < 255u);
    cell0 = ((unsigned)zlo << 6) | ((unsigned)ylo << 3) | (unsigned)xlo;
    unsigned lx0 = (unsigned)(x0 - (xlo << 5) + 1);
    unsigned ly0 = (unsigned)(y0 - (ylo << 5) + 1);
    unsigned lz0 = (unsigned)(z0 - (zlo << 4) + 1);
    w1base = e.pk | (lx0 << 14) | (ly0 << 20) | (lz0 << 26);
    return true;
}

__global__ void init_kernel(unsigned* __restrict__ gCursor,
                            int* __restrict__ lossAcc,
                            unsigned* __restrict__ doneCnt) {
    int t = threadIdx.x;
    gCursor[t] = 0;
    if (t == 0) { lossAcc[0] = 0; doneCnt[0] = 0; }
}

// Binning: LDS histogram -> even-padded scan -> global per-cell reservation
// (latency hidden under the LDS scatter) -> LDS scatter (4 B items + u16
// cell tag; zero-sentinel pad per odd run) -> uint2 writeout (2 items, 8 B,
// pairs never straddle runs) to CELL-CONTIGUOUS global layout.
__global__ __launch_bounds__(1024) void bin_kernel(
    const float* __restrict__ pred, const float* __restrict__ gt,
    const float* __restrict__ coords, unsigned* __restrict__ gCursor,
    unsigned* __restrict__ payload, int n) {
    __shared__ unsigned h[NCELLS];            // 4 KB (histogram, then cursor)
    __shared__ unsigned gAdj[NCELLS];         // 4 KB dest-adjust per cell
    __shared__ unsigned short itemCell[BCAP]; // 12 KB cell tag per staged item
    __shared__ unsigned wtot[16];
    __shared__ unsigned totalS;
    __shared__ unsigned pl[BCAP];             // 24 KB payload staging (4 B/item)
    int b = blockIdx.x;
    int t = threadIdx.x;
    h[t] = 0;
    __syncthreads();

    int chunk = (n + NB - 1) / NB;
    int start = b * chunk;
    int end = min(start + chunk, n);
    const float3* c3 = (const float3*)coords;
    const float3* p3 = (const float3*)pred;
    const float3* g3 = (const float3*)gt;

    CEv ev[2 * NPT];
#pragma unroll
    for (int k = 0; k < NPT; ++k) {
        int i = start + t + (k << 10);
        if (i < end) {
            float3 c = c3[i];
            float3 p = p3[i];
            float3 g = g3[i];
            ev[2 * k] = make_cev(c.x + p.x, c.y + p.y, c.z + p.z, 0u);
            ev[2 * k + 1] = make_cev(c.x + g.x, c.y + g.y, c.z + g.z, 1u);
        } else {
            ev[2 * k].xyz = 0;
            ev[2 * k + 1].xyz = 0;
        }
    }

    // pass 1: histogram (branch-free 8-corner, predicated LDS atomics)
#pragma unroll
    for (int k = 0; k < 2 * NPT; ++k) {
        unsigned cell0, w1base;
        bool bx, by, bz;
        if (ev_flat(ev[k], cell0, w1base, bx, by, bz)) {
#pragma unroll
            for (int q = 0; q < 8; ++q) {
                const int DX = q & 1, DY = (q >> 1) & 1, DZ = q >> 2;
                bool go = (DX ? bx : true) & (DY ? by : true) & (DZ ? bz : true);
                if (go) atomicAdd(&h[cell0 + DX + 8 * DY + 64 * DZ], 1u);
            }
        }
    }
    __syncthreads();

    // exclusive scan over EVEN-PADDED counts (xp = x rounded up to even)
    unsigned x = h[t];
    unsigned xp = x + (x & 1u);
    unsigned incl = xp;
    int lane = t & 63, wid = t >> 6;
#pragma unroll
    for (int off = 1; off < 64; off <<= 1) {
        unsigned y = __shfl_up(incl, off, 64);
        if (lane >= off) incl += y;
    }
    if (lane == 63) wtot[wid] = incl;
    __syncthreads();
    if (t == 0) {
        unsigned r = 0;
#pragma unroll
        for (int w = 0; w < 16; ++w) { unsigned q = wtot[w]; wtot[w] = r; r += q; }
        totalS = r;
    }
    __syncthreads();
    unsigned offE = incl - xp + wtot[wid];  // even
    h[t] = offE;  // reuse as scatter cursor

    // zero-sentinel pad for odd runs (pk=0 decodes to exact-zero weights:
    // all fractions 0 -> every surviving corner gets iw = round(0) = 0)
    if ((x & 1u) && (offE + x) < (unsigned)BCAP) {
        pl[offE + x] = 0u;
        itemCell[offE + x] = (unsigned short)t;
    }

    // global per-cell reservation of the PADDED count (latency hidden under
    // the scatter phase)
    unsigned gdst = atomicAdd(&gCursor[t], xp);  // even since all xp even
    gAdj[t] = (unsigned)t * (unsigned)CCAP + gdst - offE;  // even; u32 wrap ok
    __syncthreads();

    // pass 2: scatter into LDS staging + cell tag (branch-free 8-corner;
    // per-corner w1 is a constant field subtraction off w1base)
#pragma unroll
    for (int k = 0; k < 2 * NPT; ++k) {
        unsigned cell0, w1base;
        bool bx, by, bz;
        if (ev_flat(ev[k], cell0, w1base, bx, by, bz)) {
#pragma unroll
            for (int q = 0; q < 8; ++q) {
                const int DX = q & 1, DY = (q >> 1) & 1, DZ = q >> 2;
                bool go = (DX ? bx : true) & (DY ? by : true) & (DZ ? bz : true);
                if (go) {
                    unsigned cell = cell0 + DX + 8 * DY + 64 * DZ;
                    unsigned w1 = w1base - (((unsigned)DX << 19) +
                                            ((unsigned)DY << 25) +
                                            ((unsigned)DZ << 30));
                    unsigned slot = atomicAdd(&h[cell], 1u);
                    if (slot < (unsigned)BCAP) {
                        pl[slot] = w1;
                        itemCell[slot] = (unsigned short)cell;
                    }
                }
            }
        }
    }
    __syncthreads();

    // writeout: uint2 stores (2 items, 8 B; pairs never straddle runs)
    unsigned tot = min(totalS, (unsigned)BCAP);
    unsigned np = tot >> 1;
    const uint2* pl2 = (const uint2*)pl;
    uint2* pay2 = (uint2*)payload;
    for (unsigned j = t; j < np; j += 1024) {
        unsigned cell = itemCell[2 * j];
        unsigned e = gAdj[cell] + 2u * j;   // even element index
        if (e + 2u <= (cell + 1u) * (unsigned)CCAP) pay2[e >> 1] = pl2[j];
    }
}

__device__ __forceinline__ void accum_item(unsigned p, int* v) {
    float fx = (float)(p & 31u) * (1.0f / 31.0f);
    float fy = (float)((p >> 5) & 31u) * (1.0f / 31.0f);
    float fz = (float)((p >> 10) & 15u) * (1.0f / 15.0f);
    int lx = (int)((p >> 14) & 63u);
    int ly = (int)((p >> 20) & 63u);
    int lz = (int)((p >> 26) & 31u);
    float s = (p >> 31) ? -W_SCALE : W_SCALE;
    float wxs[2] = {1.0f - fx, fx};
    float wys[2] = {1.0f - fy, fy};
    float wzs[2] = {1.0f - fz, fz};
    int xb = lx - 1, yb = ly - 1, zb = lz - 1;
#pragma unroll
    for (int dz = 0; dz < 2; ++dz) {
        int rz = zb + dz;
        if ((unsigned)rz > 15u) continue;
        float wz = s * wzs[dz];
#pragma unroll
        for (int dy = 0; dy < 2; ++dy) {
            int ry = yb + dy;
            if ((unsigned)ry > 31u) continue;
            float wyz = wz * wys[dy];
#pragma unroll
            for (int dx = 0; dx < 2; ++dx) {
                int rx = xb + dx;
                if ((unsigned)rx > 31u) continue;
                int iw = __float2int_rn(wyz * wxs[dx]);
                atomicAdd(&v[(rz << 10) | (ry << 5) | rx], iw);  // ds_add, no ret
            }
        }
    }
}

// One block per cell: payload is cell-contiguous -> pure streaming uint2
// reads (2 items each), zero indirection. Count is even (padded); sentinels
// add exactly zero. Per-block wsum reduction + ONE lossAcc atomic per block.
__global__ __launch_bounds__(1024) void accum_kernel(
    const unsigned* __restrict__ payload, const unsigned* __restrict__ gCursor,
    int* __restrict__ lossAcc, unsigned* __restrict__ doneCnt,
    float* __restrict__ out) {
    __shared__ int4 v4s[4096];                   // 64 KB accumulation grid
    __shared__ float wsum[16];
    int* v = (int*)v4s;
    int c = blockIdx.x;
    int t = threadIdx.x;
    unsigned cnt = min(gCursor[c], (unsigned)CCAP) & ~1u;  // uniform: s_load
    int4 z; z.x = 0; z.y = 0; z.z = 0; z.w = 0;
#pragma unroll
    for (int j = 0; j < 4; ++j) v4s[t + (j << 10)] = z;
    __syncthreads();

    const uint2* p2 = (const uint2*)(payload + (size_t)c * CCAP);  // 8B aligned
    unsigned n2 = cnt >> 1;
#pragma unroll 2
    for (unsigned i = t; i < n2; i += 1024) {
        uint2 q = p2[i];
        accum_item(q.x, v);
        accum_item(q.y, v);
    }
    __syncthreads();

    int lane = t & 63, wid = t >> 6;
    float acc = 0.0f;
#pragma unroll
    for (int j = 0; j < 4; ++j) {
        int4 q = v4s[t + (j << 10)];
        {
            float d = (float)q.x * INV_W;
            float ad = fabsf(d);
            acc += (ad <= 1.0f) ? 0.5f * d * d : ad - 0.5f;
        }
        {
            float d = (float)q.y * INV_W;
            float ad = fabsf(d);
            acc += (ad <= 1.0f) ? 0.5f * d * d : ad - 0.5f;
        }
        {
            float d = (float)q.z * INV_W;
            float ad = fabsf(d);
            acc += (ad <= 1.0f) ? 0.5f * d * d : ad - 0.5f;
        }
        {
            float d = (float)q.w * INV_W;
            float ad = fabsf(d);
            acc += (ad <= 1.0f) ? 0.5f * d * d : ad - 0.5f;
        }
    }
#pragma unroll
    for (int o = 32; o > 0; o >>= 1) acc += __shfl_down(acc, o, 64);
    if (lane == 0) wsum[wid] = acc;
    __syncthreads();
    if (t == 0) {
        float tsum = 0.0f;
#pragma unroll
        for (int w = 0; w < 16; ++w) tsum += wsum[w];
        atomicAdd(lossAcc, __float2int_rn(tsum * L_SCALE));
        __threadfence();
        unsigned done = atomicAdd(doneCnt, 1u);
        if (done == (unsigned)(NCELLS - 1)) {   // last block finalizes
            __threadfence();
            int lv = atomicAdd(lossAcc, 0);
            out[0] = (float)lv * INV_L;
        }
    }
}

extern "C" void kernel_launch(void* const* d_in, const int* in_sizes, int n_in,
                              void* d_out, int out_size, void* d_ws, size_t ws_size,
                              hipStream_t stream) {
    const float* reg_pred = (const float*)d_in[0];
    const float* reg_gt   = (const float*)d_in[1];
    const float* coords   = (const float*)d_in[2];
    float* out = (float*)d_out;

    char* ws = (char*)d_ws;
    int* lossAcc = (int*)ws;                                  // 4 B
    unsigned* doneCnt = (unsigned*)(ws + 64);                 // 4 B
    unsigned* gCursor = (unsigned*)(ws + 256);                // 4 KiB
    unsigned* payload = (unsigned*)(ws + 256 + 4096);         // 24 MiB

    int n = in_sizes[0] / 3;  // 2,000,000 points

    init_kernel<<<1, 1024, 0, stream>>>(gCursor, lossAcc, doneCnt);
    bin_kernel<<<NB, 1024, 0, stream>>>(reg_pred, reg_gt, coords, gCursor,
                                        payload, n);
    accum_kernel<<<NCELLS, 1024, 0, stream>>>(payload, gCursor, lossAcc,
                                              doneCnt, out);
}

// Round 14
// 149.101 us; speedup vs baseline: 2.1335x; 1.0494x over previous
//
#include <hip/hip_runtime.h>

#define GRID_RES 256
#define NCELLS 1024            // 8 x 8 x 16 cells of 32 x 32 x 16 voxels
#define NB 512                 // binning blocks (all co-resident: 2/CU x 256 CU)
#define BCAP 12160             // per-block LDS staging capacity (expected ~9340 padded)
#define CCAP 6144              // per-cell global region capacity (even; expected ~4800 max)
#define NPT 4                  // points per thread in bin (chunk 3907 <= 4*1024)

#define W_SCALE 2097152.0f     // 2^21 fixed-point for voxel weights
#define INV_W (1.0f / 2097152.0f)
#define L_SCALE 512.0f         // 2^9 fixed-point for the loss accumulator
#define INV_L (1.0f / 512.0f)

// 4-byte packed event item:
//   bits [0,5)   qx (fx * 31, RN)        dequant * (1/31)
//   bits [5,10)  qy (fy * 31, RN)
//   bits [10,14) qz (fz * 15, RN)        dequant * (1/15)
//   bits [14,20) lx in [0,32]  (base-cell local coords, biased +1)
//   bits [20,26) ly in [0,32]
//   bits [26,31) lz in [0,16]
//   bit  31      sign (0 = pred +, 1 = gt -)
// NOTE (round-12 A/B): per-wave global atomics on lossAcc (16K same-address
// device-scope atomics) serialized cross-XCD and cost +150 us -- keep the
// per-block wsum reduction + ONE atomic per block (Guideline 12).
// NOTE (round-11 A/B): direct scattered 4 B global stores instead of LDS
// staging cost +21 us and +35 MB WRITE_SIZE -- staging is load-bearing.
struct CEv { unsigned pk, xyz; };

__device__ __forceinline__ CEv make_cev(float px, float py, float pz,
                                        unsigned sign) {
    float x = ((px + 1.0f) * (float)GRID_RES - 1.0f) * 0.5f;
    float y = ((py + 1.0f) * (float)GRID_RES - 1.0f) * 0.5f;
    float z = ((pz + 1.0f) * (float)GRID_RES - 1.0f) * 0.5f;
    float xf = floorf(x), yf = floorf(y), zf = floorf(z);
    int x0 = (int)xf, y0 = (int)yf, z0 = (int)zf;
    unsigned qx = (unsigned)((x - xf) * 31.0f + 0.5f);   // 0..31
    unsigned qy = (unsigned)((y - yf) * 31.0f + 0.5f);   // 0..31
    unsigned qz = (unsigned)((z - zf) * 15.0f + 0.5f);   // 0..15
    bool valid = (x0 >= -1) & (x0 <= 255) & (y0 >= -1) & (y0 <= 255) &
                 (z0 >= -1) & (z0 <= 255);
    CEv e;
    e.pk = qx | (qy << 5) | (qz << 10) | (sign << 31);
    e.xyz = valid ? ((unsigned)(x0 + 1) | ((unsigned)(y0 + 1) << 10) |
                     ((unsigned)(z0 + 1) << 20) | (1u << 30))
                  : 0u;
    return e;
}

// Flat decode for branch-free 8-corner cell enumeration.
// cell0 = base cell; bx/by/bz = "second cell exists" per axis;
// w1base = pk with base-cell local coords OR'd in (lx0 = 32 whenever bx,
// so the per-corner field subtraction never borrows).
__device__ __forceinline__ bool ev_flat(const CEv& e, unsigned& cell0,
                                        unsigned& w1base, bool& bx, bool& by,
                                        bool& bz) {
    if (!(e.xyz & (1u << 30))) return false;
    int x0 = (int)(e.xyz & 1023u) - 1;
    int y0 = (int)((e.xyz >> 10) & 1023u) - 1;
    int z0 = (int)((e.xyz >> 20) & 1023u) - 1;
    int xlo = (x0 >= 0) ? (x0 >> 5) : 0;
    int ylo = (y0 >= 0) ? (y0 >> 5) : 0;
    int zlo = (z0 >= 0) ? (z0 >> 4) : 0;
    bx = ((x0 & 31) == 31) & ((unsigned)x0 < 255u);
    by = ((y0 & 31) == 31) & ((unsigned)y0 < 255u);
    bz = ((z0 & 15) == 15) & ((unsigned)z0 < 255u);
    cell0 = ((unsigned)zlo << 6) | ((unsigned)ylo << 3) | (unsigned)xlo;
    unsigned lx0 = (unsigned)(x0 - (xlo << 5) + 1);
    unsigned ly0 = (unsigned)(y0 - (ylo << 5) + 1);
    unsigned lz0 = (unsigned)(z0 - (zlo << 4) + 1);
    w1base = e.pk | (lx0 << 14) | (ly0 << 20) | (lz0 << 26);
    return true;
}

__global__ void init_kernel(unsigned* __restrict__ gCursor,
                            int* __restrict__ lossAcc,
                            unsigned* __restrict__ doneCnt) {
    int t = threadIdx.x;
    gCursor[t] = 0;
    if (t == 0) { lossAcc[0] = 0; doneCnt[0] = 0; }
}

// Binning: LDS histogram -> even-padded scan -> global per-cell reservation
// (latency hidden under the LDS scatter) -> LDS scatter (4 B items + u16
// cell tag; zero-sentinel pad per odd run) -> uint2 writeout (2 items, 8 B,
// pairs never straddle runs) to CELL-CONTIGUOUS global layout.
// NB=512 / NPT=4: per-block fixed costs (cell-scan, init, writeout setup)
// amortized over 2x points; all 512 blocks co-resident (2/CU, 79.3 KB LDS).
__global__ __launch_bounds__(1024) void bin_kernel(
    const float* __restrict__ pred, const float* __restrict__ gt,
    const float* __restrict__ coords, unsigned* __restrict__ gCursor,
    unsigned* __restrict__ payload, int n) {
    __shared__ unsigned h[NCELLS];            // 4 KB (histogram, then cursor)
    __shared__ unsigned gAdj[NCELLS];         // 4 KB dest-adjust per cell
    __shared__ unsigned short itemCell[BCAP]; // 23.75 KB cell tag per staged item
    __shared__ unsigned wtot[16];
    __shared__ unsigned totalS;
    __shared__ unsigned pl[BCAP];             // 47.5 KB payload staging (4 B/item)
    int b = blockIdx.x;
    int t = threadIdx.x;
    h[t] = 0;
    __syncthreads();

    int chunk = (n + NB - 1) / NB;
    int start = b * chunk;
    int end = min(start + chunk, n);
    const float3* c3 = (const float3*)coords;
    const float3* p3 = (const float3*)pred;
    const float3* g3 = (const float3*)gt;

    CEv ev[2 * NPT];
#pragma unroll
    for (int k = 0; k < NPT; ++k) {
        int i = start + t + (k << 10);
        if (i < end) {
            float3 c = c3[i];
            float3 p = p3[i];
            float3 g = g3[i];
            ev[2 * k] = make_cev(c.x + p.x, c.y + p.y, c.z + p.z, 0u);
            ev[2 * k + 1] = make_cev(c.x + g.x, c.y + g.y, c.z + g.z, 1u);
        } else {
            ev[2 * k].xyz = 0;
            ev[2 * k + 1].xyz = 0;
        }
    }

    // pass 1: histogram (branch-free 8-corner, predicated LDS atomics)
#pragma unroll
    for (int k = 0; k < 2 * NPT; ++k) {
        unsigned cell0, w1base;
        bool bx, by, bz;
        if (ev_flat(ev[k], cell0, w1base, bx, by, bz)) {
#pragma unroll
            for (int q = 0; q < 8; ++q) {
                const int DX = q & 1, DY = (q >> 1) & 1, DZ = q >> 2;
                bool go = (DX ? bx : true) & (DY ? by : true) & (DZ ? bz : true);
                if (go) atomicAdd(&h[cell0 + DX + 8 * DY + 64 * DZ], 1u);
            }
        }
    }
    __syncthreads();

    // exclusive scan over EVEN-PADDED counts (xp = x rounded up to even)
    unsigned x = h[t];
    unsigned xp = x + (x & 1u);
    unsigned incl = xp;
    int lane = t & 63, wid = t >> 6;
#pragma unroll
    for (int off = 1; off < 64; off <<= 1) {
        unsigned y = __shfl_up(incl, off, 64);
        if (lane >= off) incl += y;
    }
    if (lane == 63) wtot[wid] = incl;
    __syncthreads();
    if (t == 0) {
        unsigned r = 0;
#pragma unroll
        for (int w = 0; w < 16; ++w) { unsigned q = wtot[w]; wtot[w] = r; r += q; }
        totalS = r;
    }
    __syncthreads();
    unsigned offE = incl - xp + wtot[wid];  // even
    h[t] = offE;  // reuse as scatter cursor

    // zero-sentinel pad for odd runs (pk=0 decodes to exact-zero weights:
    // all fractions 0 -> every surviving corner gets iw = round(0) = 0)
    if ((x & 1u) && (offE + x) < (unsigned)BCAP) {
        pl[offE + x] = 0u;
        itemCell[offE + x] = (unsigned short)t;
    }

    // global per-cell reservation of the PADDED count (latency hidden under
    // the scatter phase)
    unsigned gdst = atomicAdd(&gCursor[t], xp);  // even since all xp even
    gAdj[t] = (unsigned)t * (unsigned)CCAP + gdst - offE;  // even; u32 wrap ok
    __syncthreads();

    // pass 2: scatter into LDS staging + cell tag (branch-free 8-corner;
    // per-corner w1 is a constant field subtraction off w1base)
#pragma unroll
    for (int k = 0; k < 2 * NPT; ++k) {
        unsigned cell0, w1base;
        bool bx, by, bz;
        if (ev_flat(ev[k], cell0, w1base, bx, by, bz)) {
#pragma unroll
            for (int q = 0; q < 8; ++q) {
                const int DX = q & 1, DY = (q >> 1) & 1, DZ = q >> 2;
                bool go = (DX ? bx : true) & (DY ? by : true) & (DZ ? bz : true);
                if (go) {
                    unsigned cell = cell0 + DX + 8 * DY + 64 * DZ;
                    unsigned w1 = w1base - (((unsigned)DX << 19) +
                                            ((unsigned)DY << 25) +
                                            ((unsigned)DZ << 30));
                    unsigned slot = atomicAdd(&h[cell], 1u);
                    if (slot < (unsigned)BCAP) {
                        pl[slot] = w1;
                        itemCell[slot] = (unsigned short)cell;
                    }
                }
            }
        }
    }
    __syncthreads();

    // writeout: uint2 stores (2 items, 8 B; pairs never straddle runs)
    unsigned tot = min(totalS, (unsigned)BCAP);
    unsigned np = tot >> 1;
    const uint2* pl2 = (const uint2*)pl;
    uint2* pay2 = (uint2*)payload;
    for (unsigned j = t; j < np; j += 1024) {
        unsigned cell = itemCell[2 * j];
        unsigned e = gAdj[cell] + 2u * j;   // even element index
        if (e + 2u <= (cell + 1u) * (unsigned)CCAP) pay2[e >> 1] = pl2[j];
    }
}

__device__ __forceinline__ void accum_item(unsigned p, int* v) {
    float fx = (float)(p & 31u) * (1.0f / 31.0f);
    float fy = (float)((p >> 5) & 31u) * (1.0f / 31.0f);
    float fz = (float)((p >> 10) & 15u) * (1.0f / 15.0f);
    int lx = (int)((p >> 14) & 63u);
    int ly = (int)((p >> 20) & 63u);
    int lz = (int)((p >> 26) & 31u);
    float s = (p >> 31) ? -W_SCALE : W_SCALE;
    float wxs[2] = {1.0f - fx, fx};
    float wys[2] = {1.0f - fy, fy};
    float wzs[2] = {1.0f - fz, fz};
    int xb = lx - 1, yb = ly - 1, zb = lz - 1;
#pragma unroll
    for (int dz = 0; dz < 2; ++dz) {
        int rz = zb + dz;
        if ((unsigned)rz > 15u) continue;
        float wz = s * wzs[dz];
#pragma unroll
        for (int dy = 0; dy < 2; ++dy) {
            int ry = yb + dy;
            if ((unsigned)ry > 31u) continue;
            float wyz = wz * wys[dy];
#pragma unroll
            for (int dx = 0; dx < 2; ++dx) {
                int rx = xb + dx;
                if ((unsigned)rx > 31u) continue;
                int iw = __float2int_rn(wyz * wxs[dx]);
                atomicAdd(&v[(rz << 10) | (ry << 5) | rx], iw);  // ds_add, no ret
            }
        }
    }
}

// One block per cell: payload is cell-contiguous -> pure streaming uint2
// reads (2 items each), zero indirection. Count is even (padded); sentinels
// add exactly zero. Per-block wsum reduction + ONE lossAcc atomic per block.
__global__ __launch_bounds__(1024) void accum_kernel(
    const unsigned* __restrict__ payload, const unsigned* __restrict__ gCursor,
    int* __restrict__ lossAcc, unsigned* __restrict__ doneCnt,
    float* __restrict__ out) {
    __shared__ int4 v4s[4096];                   // 64 KB accumulation grid
    __shared__ float wsum[16];
    int* v = (int*)v4s;
    int c = blockIdx.x;
    int t = threadIdx.x;
    unsigned cnt = min(gCursor[c], (unsigned)CCAP) & ~1u;  // uniform: s_load
    int4 z; z.x = 0; z.y = 0; z.z = 0; z.w = 0;
#pragma unroll
    for (int j = 0; j < 4; ++j) v4s[t + (j << 10)] = z;
    __syncthreads();

    const uint2* p2 = (const uint2*)(payload + (size_t)c * CCAP);  // 8B aligned
    unsigned n2 = cnt >> 1;
#pragma unroll 2
    for (unsigned i = t; i < n2; i += 1024) {
        uint2 q = p2[i];
        accum_item(q.x, v);
        accum_item(q.y, v);
    }
    __syncthreads();

    int lane = t & 63, wid = t >> 6;
    float acc = 0.0f;
#pragma unroll
    for (int j = 0; j < 4; ++j) {
        int4 q = v4s[t + (j << 10)];
        {
            float d = (float)q.x * INV_W;
            float ad = fabsf(d);
            acc += (ad <= 1.0f) ? 0.5f * d * d : ad - 0.5f;
        }
        {
            float d = (float)q.y * INV_W;
            float ad = fabsf(d);
            acc += (ad <= 1.0f) ? 0.5f * d * d : ad - 0.5f;
        }
        {
            float d = (float)q.z * INV_W;
            float ad = fabsf(d);
            acc += (ad <= 1.0f) ? 0.5f * d * d : ad - 0.5f;
        }
        {
            float d = (float)q.w * INV_W;
            float ad = fabsf(d);
            acc += (ad <= 1.0f) ? 0.5f * d * d : ad - 0.5f;
        }
    }
#pragma unroll
    for (int o = 32; o > 0; o >>= 1) acc += __shfl_down(acc, o, 64);
    if (lane == 0) wsum[wid] = acc;
    __syncthreads();
    if (t == 0) {
        float tsum = 0.0f;
#pragma unroll
        for (int w = 0; w < 16; ++w) tsum += wsum[w];
        atomicAdd(lossAcc, __float2int_rn(tsum * L_SCALE));
        __threadfence();
        unsigned done = atomicAdd(doneCnt, 1u);
        if (done == (unsigned)(NCELLS - 1)) {   // last block finalizes
            __threadfence();
            int lv = atomicAdd(lossAcc, 0);
            out[0] = (float)lv * INV_L;
        }
    }
}

extern "C" void kernel_launch(void* const* d_in, const int* in_sizes, int n_in,
                              void* d_out, int out_size, void* d_ws, size_t ws_size,
                              hipStream_t stream) {
    const float* reg_pred = (const float*)d_in[0];
    const float* reg_gt   = (const float*)d_in[1];
    const float* coords   = (const float*)d_in[2];
    float* out = (float*)d_out;

    char* ws = (char*)d_ws;
    int* lossAcc = (int*)ws;                                  // 4 B
    unsigned* doneCnt = (unsigned*)(ws + 64);                 // 4 B
    unsigned* gCursor = (unsigned*)(ws + 256);                // 4 KiB
    unsigned* payload = (unsigned*)(ws + 256 + 4096);         // 24 MiB

    int n = in_sizes[0] / 3;  // 2,000,000 points

    init_kernel<<<1, 1024, 0, stream>>>(gCursor, lossAcc, doneCnt);
    bin_kernel<<<NB, 1024, 0, stream>>>(reg_pred, reg_gt, coords, gCursor,
                                        payload, n);
    accum_kernel<<<NCELLS, 1024, 0, stream>>>(payload, gCursor, lossAcc,
                                              doneCnt, out);
}